// Round 6
// baseline (14385.619 us; speedup 1.0000x reference)
//
#include <hip/hip_runtime.h>

typedef unsigned short u16;
typedef unsigned int u32;
typedef __attribute__((ext_vector_type(8))) short short8;
typedef __attribute__((ext_vector_type(4))) short short4_t;
typedef __attribute__((ext_vector_type(4))) float f32x4;
typedef const __attribute__((address_space(1))) u32 gu32;
typedef __attribute__((address_space(3))) u32 lu32;

#define NBLK 512
#define BDIM 256
#define NPHASE 256

__device__ inline u16 f2bf(float f){
  unsigned u = __float_as_uint(f);
  return (u16)((u + 0x7FFFu + ((u>>16)&1u)) >> 16);
}
__device__ inline float bf2f(u16 h){ return __uint_as_float(((unsigned)h)<<16); }
__device__ inline void splitw(float f, u16 &hi, u16 &lo){
  hi = f2bf(f);
  lo = f2bf(f - bf2f(hi));
}
__device__ inline void gll16(const void* g, void* l){
  __builtin_amdgcn_global_load_lds((gu32*)g, (lu32*)l, 16, 0, 0);
}

// Device-scope grid barrier, one counter per phase (memset to 0 each launch).
// Release: __syncthreads (drains vmcnt per wave) + threadfence (agent-scope L2
// writeback) before the add; Acquire: threadfence (L2 inv) after full count.
__device__ inline void gridbar(int* cnt, int ph){
  __syncthreads();
  if (threadIdx.x == 0){
    __threadfence();
    atomicAdd(&cnt[ph], 1);
    while (__hip_atomic_load(&cnt[ph], __ATOMIC_RELAXED, __HIP_MEMORY_SCOPE_AGENT) < NBLK)
      __builtin_amdgcn_s_sleep(2);
    __threadfence();
  }
  __syncthreads();
}

// W[k][n] (1024x1024 row-major) -> Wth/Wtl[n][k] bf16 hi/lo, tiled transpose.
__global__ __launch_bounds__(256) void prep_weights(const float* __restrict__ W,
                                                    u16* __restrict__ Wth, u16* __restrict__ Wtl){
  __shared__ float tile[32][33];
  int n0 = blockIdx.x*32, k0 = blockIdx.y*32;
  int tx = threadIdx.x & 31, ty = threadIdx.x >> 5;  // 32 x 8
  #pragma unroll
  for (int j=0;j<4;++j)
    tile[ty+8*j][tx] = W[(k0+ty+8*j)*1024 + n0 + tx];
  __syncthreads();
  #pragma unroll
  for (int j=0;j<4;++j){
    int nl = ty + 8*j;
    float f = tile[tx][nl];
    u16 hi, lo; splitw(f, hi, lo);
    Wth[(size_t)(n0+nl)*1024 + k0 + tx] = hi;
    Wtl[(size_t)(n0+nl)*1024 + k0 + tx] = lo;
  }
}

__global__ __launch_bounds__(256) void init_z(const float* __restrict__ zi, float* __restrict__ z,
                                              u16* __restrict__ zh, u16* __restrict__ zl){
  int i = blockIdx.x*256 + threadIdx.x;
  float f = zi[i];
  z[i] = f;
  u16 h,l; splitw(f,h,l);
  zh[i]=h; zl[i]=l;
}

// ONE persistent kernel, 256 phases (32 RK4 steps x 4 stages x 2 GEMMs),
// software grid barrier between phases. Per phase: R4's proven core —
// block tile 32x32, BK=128 x 8 K-steps, dbuf global_load_lds (linear LDS
// dest + pre-swizzled global src + swizzled ds_read), 4 waves = kq-split-4
// (each wave full 32x32 for its K-quarter, M2xN2 frags), plain __syncthreads
// K-loop, LDS reduction over kq aliased onto stage buf0, fused epilogue
// (tanh or RK4-stage update).
// Phase ph: step=ph>>3, sub=(ph>>1)&3, g2=ph&1.
//   g2=0: h = tanh(A@W1 + ti*wt + b1),  A = (sub==0 ? z : zm) splits -> hh/hl
//   g2=1: k = h@W2 + b2, RK4 stage-sub updates -> zm or z splits, z, zacc
__global__ __launch_bounds__(256, 2) void ode_persistent(
    const u16* __restrict__ W1h, const u16* __restrict__ W1l,
    const u16* __restrict__ W2h, const u16* __restrict__ W2l,
    u16* __restrict__ zh,  u16* __restrict__ zl,
    u16* __restrict__ zmh, u16* __restrict__ zml,
    u16* __restrict__ hh,  u16* __restrict__ hl,
    const float* __restrict__ b1, const float* __restrict__ b2,
    const float* __restrict__ wt, const float* __restrict__ tvec,
    float* __restrict__ z, float* __restrict__ zacc, int* cnt)
{
  __shared__ char Lraw[65536];           // stage 2x32KB; red aliases buf0 [0,18432)
  float* red = (float*)Lraw;             // [4][32][36] after K-loop
  const int tid  = threadIdx.x;
  const int b    = blockIdx.x;
  const int cb   = b & 31, rbk = b >> 5; // col-block(32) [XCD-pinned cb%8] x row-block(32)
  const int kq   = tid >> 6, lane = tid & 63;
  const int lr   = lane & 15, ks = lane >> 4;

  // ---- staging geometry (chunk = 16B = 8 u16 along k) ----
  const int r0 = tid >> 4,        cc0 = tid & 15, s0 = cc0 ^ (r0 & 7);
  const int t1i = tid + 256;
  const int r1 = t1i >> 4,        cc1 = t1i & 15, s1 = cc1 ^ (r1 & 7);
  const size_t aoff0 = (size_t)(rbk*32 + r0)*1024 + s0*8;
  const size_t aoff1 = (size_t)(rbk*32 + r1)*1024 + s1*8;
  const size_t boff0 = (size_t)(cb*32 + r0)*1024 + s0*8;
  const size_t boff1 = (size_t)(cb*32 + r1)*1024 + s1*8;
  const int wb0 = (tid & ~63) * 16;      // wave-uniform LDS byte base, chunk-set 0
  const int wb1 = 4096 + wb0;            // chunk-set 1

  // ---- fragment reads: row r at byte r*256, logical chunk (kq*4+ks) ^ (r&7) ----
  const int ci = ((kq*4 + ks) ^ (lr & 7)) * 16;
  const int ro = lr*256 + ci;

  // ---- epilogue geometry: thread -> (row rr, cols c4..c4+3) ----
  const int rr = tid >> 3, c4 = (tid & 7) * 4;
  const int colb = cb*32 + c4;
  const size_t oidx = (size_t)(rbk*32 + rr)*1024 + colb;

  for (int ph = 0; ph < NPHASE; ++ph){
    const int step = ph >> 3, sub = (ph >> 1) & 3, g2 = ph & 1;
    const u16 *Ah, *Al, *Wh, *Wl;
    if (!g2){
      Ah = (sub == 0) ? zh : zmh;  Al = (sub == 0) ? zl : zml;
      Wh = W1h;  Wl = W1l;
    } else {
      Ah = hh;  Al = hl;  Wh = W2h;  Wl = W2l;
    }

    auto STAGE = [&](int bufi, int kt){
      char* L = Lraw + bufi*32768;
      const size_t ko = (size_t)kt * 128;
      gll16(Ah + aoff0 + ko, L + wb0);
      gll16(Ah + aoff1 + ko, L + wb1);
      gll16(Al + aoff0 + ko, L + 8192 + wb0);
      gll16(Al + aoff1 + ko, L + 8192 + wb1);
      gll16(Wh + boff0 + ko, L + 16384 + wb0);
      gll16(Wh + boff1 + ko, L + 16384 + wb1);
      gll16(Wl + boff0 + ko, L + 24576 + wb0);
      gll16(Wl + boff1 + ko, L + 24576 + wb1);
    };

    f32x4 a00={0.f,0.f,0.f,0.f}, a01=a00, a10=a00, a11=a00;

    STAGE(0, 0);
    __syncthreads();
    #pragma unroll
    for (int kt = 0; kt < 8; ++kt){
      const int cur = kt & 1;
      if (kt < 7) STAGE(cur ^ 1, kt + 1);
      const char* L = Lraw + cur*32768;
      short8 ah0 = *(const short8*)(L + ro);
      short8 ah1 = *(const short8*)(L + 4096  + ro);
      short8 al0 = *(const short8*)(L + 8192  + ro);
      short8 al1 = *(const short8*)(L + 12288 + ro);
      short8 bh0 = *(const short8*)(L + 16384 + ro);
      short8 bh1 = *(const short8*)(L + 20480 + ro);
      short8 bl0 = *(const short8*)(L + 24576 + ro);
      short8 bl1 = *(const short8*)(L + 28672 + ro);
      a00 = __builtin_amdgcn_mfma_f32_16x16x32_bf16(ah0, bh0, a00, 0,0,0);
      a01 = __builtin_amdgcn_mfma_f32_16x16x32_bf16(ah0, bh1, a01, 0,0,0);
      a10 = __builtin_amdgcn_mfma_f32_16x16x32_bf16(ah1, bh0, a10, 0,0,0);
      a11 = __builtin_amdgcn_mfma_f32_16x16x32_bf16(ah1, bh1, a11, 0,0,0);
      a00 = __builtin_amdgcn_mfma_f32_16x16x32_bf16(al0, bh0, a00, 0,0,0);
      a01 = __builtin_amdgcn_mfma_f32_16x16x32_bf16(al0, bh1, a01, 0,0,0);
      a10 = __builtin_amdgcn_mfma_f32_16x16x32_bf16(al1, bh0, a10, 0,0,0);
      a11 = __builtin_amdgcn_mfma_f32_16x16x32_bf16(al1, bh1, a11, 0,0,0);
      a00 = __builtin_amdgcn_mfma_f32_16x16x32_bf16(ah0, bl0, a00, 0,0,0);
      a01 = __builtin_amdgcn_mfma_f32_16x16x32_bf16(ah0, bl1, a01, 0,0,0);
      a10 = __builtin_amdgcn_mfma_f32_16x16x32_bf16(ah1, bl0, a10, 0,0,0);
      a11 = __builtin_amdgcn_mfma_f32_16x16x32_bf16(ah1, bl1, a11, 0,0,0);
      __syncthreads();
    }

    // ---- deposit kq-partials into aliased red[4][32][36] (final tile was buf1) ----
    // C/D: col=lane&15, row=(lane>>4)*4+i  [m89]
    #pragma unroll
    for (int i=0;i<4;++i){
      red[(kq*32 + ks*4 + i)*36 + lr]           = a00[i];
      red[(kq*32 + ks*4 + i)*36 + 16 + lr]      = a01[i];
      red[(kq*32 + 16 + ks*4 + i)*36 + lr]      = a10[i];
      red[(kq*32 + 16 + ks*4 + i)*36 + 16 + lr] = a11[i];
    }
    __syncthreads();

    f32x4 s = *(const f32x4*)&red[(0*32 + rr)*36 + c4];
    s += *(const f32x4*)&red[(1*32 + rr)*36 + c4];
    s += *(const f32x4*)&red[(2*32 + rr)*36 + c4];
    s += *(const f32x4*)&red[(3*32 + rr)*36 + c4];

    const float t0 = tvec[step], t1v = tvec[step+1];
    const float dt = t1v - t0, half = 0.5f*dt;

    short4_t oh, ol;
    u16 *po_h, *po_l;
    if (!g2){
      const float ti = (sub == 0) ? t0 : ((sub == 3) ? t1v : (t0 + half));
      const f32x4 bb = *(const f32x4*)&b1[colb];
      const f32x4 wv = *(const f32x4*)&wt[colb];
      #pragma unroll
      for (int j=0;j<4;++j){
        float hv = tanhf(s[j] + bb[j] + ti*wv[j]);
        u16 h,l; splitw(hv,h,l);
        oh[j] = (short)h; ol[j] = (short)l;
      }
      po_h = hh; po_l = hl;
    } else {
      const float dt6 = dt*(1.0f/6.0f), dt3 = dt*(1.0f/3.0f);
      const f32x4 bb = *(const f32x4*)&b2[colb];
      const f32x4 kv = s + bb;
      f32x4 zm;
      if (sub == 0){
        const f32x4 zv = *(const f32x4*)&z[oidx];
        zm = zv + half*kv;
        *(f32x4*)&zacc[oidx] = zv + dt6*kv;
      } else if (sub == 1){
        zm = *(const f32x4*)&z[oidx] + half*kv;
        *(f32x4*)&zacc[oidx] = *(const f32x4*)&zacc[oidx] + dt3*kv;
      } else if (sub == 2){
        zm = *(const f32x4*)&z[oidx] + dt*kv;
        *(f32x4*)&zacc[oidx] = *(const f32x4*)&zacc[oidx] + dt3*kv;
      } else {
        zm = *(const f32x4*)&zacc[oidx] + dt6*kv;
        *(f32x4*)&z[oidx] = zm;                  // z (== d_out)
      }
      #pragma unroll
      for (int j=0;j<4;++j){
        u16 h,l; splitw(zm[j],h,l);
        oh[j] = (short)h; ol[j] = (short)l;
      }
      po_h = (sub == 3) ? zh : zmh;
      po_l = (sub == 3) ? zl : zml;
    }
    *(short4_t*)&po_h[oidx] = oh;
    *(short4_t*)&po_l[oidx] = ol;

    gridbar(cnt, ph);   // release epilogue writes; acquire others' A-operand
  }
}

extern "C" void kernel_launch(void* const* d_in, const int* in_sizes, int n_in,
                              void* d_out, int out_size, void* d_ws, size_t ws_size,
                              hipStream_t stream)
{
  (void)in_sizes; (void)n_in; (void)out_size; (void)ws_size;
  const float* z_init = (const float*)d_in[0];
  const float* tvec   = (const float*)d_in[1];
  const float* W1     = (const float*)d_in[2];
  const float* b1     = (const float*)d_in[3];
  const float* wt     = (const float*)d_in[4];
  const float* W2     = (const float*)d_in[5];
  const float* b2     = (const float*)d_in[6];
  float* z = (float*)d_out;                    // fp32 master state lives in d_out

  char* p = (char*)d_ws;
  const size_t EL = 512*1024;
  u16* zh  = (u16*)p; p += EL*2;
  u16* zl  = (u16*)p; p += EL*2;
  u16* zmh = (u16*)p; p += EL*2;
  u16* zml = (u16*)p; p += EL*2;
  u16* hh  = (u16*)p; p += EL*2;
  u16* hl  = (u16*)p; p += EL*2;
  float* zacc = (float*)p; p += EL*4;
  u16* W1h = (u16*)p; p += (size_t)1024*1024*2;
  u16* W1l = (u16*)p; p += (size_t)1024*1024*2;
  u16* W2h = (u16*)p; p += (size_t)1024*1024*2;
  u16* W2l = (u16*)p; p += (size_t)1024*1024*2;
  int* cnt = (int*)p; p += NPHASE*sizeof(int);

  hipMemsetAsync(cnt, 0, NPHASE*sizeof(int), stream);
  prep_weights<<<dim3(32,32),256,0,stream>>>(W1, W1h, W1l);
  prep_weights<<<dim3(32,32),256,0,stream>>>(W2, W2h, W2l);
  init_z<<<2048,256,0,stream>>>(z_init, z, zh, zl);

  ode_persistent<<<NBLK,BDIM,0,stream>>>(W1h, W1l, W2h, W2l,
                                         zh, zl, zmh, zml, hh, hl,
                                         b1, b2, wt, tvec, z, zacc, cnt);
}

// Round 7
// 2332.163 us; speedup vs baseline: 6.1684x; 6.1684x over previous
//
#include <hip/hip_runtime.h>

typedef unsigned short u16;
typedef unsigned int u32;
typedef __attribute__((ext_vector_type(8))) short short8;
typedef __attribute__((ext_vector_type(4))) short short4_t;
typedef __attribute__((ext_vector_type(4))) float f32x4;
typedef const __attribute__((address_space(1))) u32 gu32;
typedef __attribute__((address_space(3))) u32 lu32;

#define NGRID 512
#define BDIM 256

__device__ inline u16 f2bf(float f){
  unsigned u = __float_as_uint(f);
  return (u16)((u + 0x7FFFu + ((u>>16)&1u)) >> 16);
}
__device__ inline float bf2f(u16 h){ return __uint_as_float(((unsigned)h)<<16); }
__device__ inline void splitw(float f, u16 &hi, u16 &lo){
  hi = f2bf(f);
  lo = f2bf(f - bf2f(hi));
}
__device__ inline void gll16(const void* g, void* l){
  __builtin_amdgcn_global_load_lds((gu32*)g, (lu32*)l, 16, 0, 0);
}

// W[k][n] (1024x1024 row-major) -> Wth/Wtl[n][k] bf16 hi/lo, tiled transpose.
__global__ __launch_bounds__(256) void prep_weights(const float* __restrict__ W,
                                                    u16* __restrict__ Wth, u16* __restrict__ Wtl){
  __shared__ float tile[32][33];
  int n0 = blockIdx.x*32, k0 = blockIdx.y*32;
  int tx = threadIdx.x & 31, ty = threadIdx.x >> 5;  // 32 x 8
  #pragma unroll
  for (int j=0;j<4;++j)
    tile[ty+8*j][tx] = W[(k0+ty+8*j)*1024 + n0 + tx];
  __syncthreads();
  #pragma unroll
  for (int j=0;j<4;++j){
    int nl = ty + 8*j;
    float f = tile[tx][nl];
    u16 hi, lo; splitw(f, hi, lo);
    Wth[(size_t)(n0+nl)*1024 + k0 + tx] = hi;
    Wtl[(size_t)(n0+nl)*1024 + k0 + tx] = lo;
  }
}

__global__ __launch_bounds__(256) void init_z(const float* __restrict__ zi, float* __restrict__ z,
                                              u16* __restrict__ zh, u16* __restrict__ zl){
  int i = blockIdx.x*256 + threadIdx.x;
  float f = zi[i];
  z[i] = f;
  u16 h,l; splitw(f,h,l);
  zh[i]=h; zl[i]=l;
}

// R4 champion structure + R7 additions:
//  - prologue prefetch of epilogue operands (bias/wt/z/zacc) into regs, issue
//    pinned before the K-loop so their ~400-900cy global latency hides under GEMM
//  - s_setprio(1) around the MFMA cluster (T5)
// Core: block tile 32x32, BK=128 x 8 K-steps, dbuf global_load_lds staging
// (linear LDS dest + pre-swizzled global src + swizzled ds_read), 256 thr,
// 4 waves = kq-split-4 (each wave full 32x32 for its K-quarter, M2xN2 frags),
// plain __syncthreads K-loop, LDS kq-reduction aliased onto stage buf0,
// fused epilogue. LDS 64KB -> 2 blocks/CU.
// MODE 0: h = tanh(A@W1 + ti*wt + b1); MODE 1+s: k = A@W2 + b2 + RK4 stage-s.
template<int MODE>
__global__ __launch_bounds__(256, 2) void fused_gemm(
    const u16* __restrict__ Ahi, const u16* __restrict__ Alo,   // [512][1024]
    const u16* __restrict__ Wth, const u16* __restrict__ Wtl,   // [1024][1024] (n-major)
    const float* __restrict__ bias, const float* __restrict__ wtv,
    const float* __restrict__ tvec, int step, int which,
    u16* __restrict__ OutHi, u16* __restrict__ OutLo,
    float* __restrict__ Zbuf, float* __restrict__ Zacc)
{
  __shared__ char Lraw[65536];           // stage 2x32KB; red aliases buf0 [0,18432)
  float* red = (float*)Lraw;             // [4][32][36] after K-loop
  const int tid  = threadIdx.x;
  const int b    = blockIdx.x;
  const int cb   = b & 31, rbk = b >> 5; // col-block(32) [XCD-pinned cb%8] x row-block(32)
  const int kq   = tid >> 6, lane = tid & 63;
  const int lr   = lane & 15, ks = lane >> 4;

  // ---- staging (chunk = 16B = 8 u16 along k; linear LDS dest, pre-swizzled src) ----
  const int r0 = tid >> 4,        cc0 = tid & 15, s0 = cc0 ^ (r0 & 7);
  const int t1i = tid + 256;
  const int r1 = t1i >> 4,        cc1 = t1i & 15, s1 = cc1 ^ (r1 & 7);
  const size_t a0 = (size_t)(rbk*32 + r0)*1024 + s0*8;
  const size_t a1 = (size_t)(rbk*32 + r1)*1024 + s1*8;
  const size_t b0 = (size_t)(cb*32 + r0)*1024 + s0*8;
  const size_t b1 = (size_t)(cb*32 + r1)*1024 + s1*8;
  const int wb0 = (tid & ~63) * 16;      // wave-uniform LDS byte base, chunk-set 0
  const int wb1 = 4096 + wb0;            // chunk-set 1

  auto STAGE = [&](int bufi, int kt){
    char* L = Lraw + bufi*32768;
    const size_t ko = (size_t)kt * 128;
    gll16(Ahi + a0 + ko, L + wb0);
    gll16(Ahi + a1 + ko, L + wb1);
    gll16(Alo + a0 + ko, L + 8192 + wb0);
    gll16(Alo + a1 + ko, L + 8192 + wb1);
    gll16(Wth + b0 + ko, L + 16384 + wb0);
    gll16(Wth + b1 + ko, L + 16384 + wb1);
    gll16(Wtl + b0 + ko, L + 24576 + wb0);
    gll16(Wtl + b1 + ko, L + 24576 + wb1);
  };

  // ---- fragment reads: row r at byte r*256, logical chunk (kq*4+ks) ^ (r&7) ----
  const int ci = ((kq*4 + ks) ^ (lr & 7)) * 16;
  const int ro = lr*256 + ci;            // shared by A rows (lr) and B cols (lr)

  // ---- epilogue geometry (needed early for prefetch) ----
  const int rr = tid >> 3, c4 = (tid & 7) * 4;
  const int colb = cb*32 + c4;
  const size_t oidx = (size_t)(rbk*32 + rr)*1024 + colb;

  // ---- prologue prefetch of epilogue operands (hidden under the K-loop) ----
  f32x4 pre_b = *(const f32x4*)&bias[colb];
  f32x4 pre_w = {0.f,0.f,0.f,0.f};
  f32x4 pre_z = {0.f,0.f,0.f,0.f};
  f32x4 pre_a = {0.f,0.f,0.f,0.f};
  if constexpr (MODE == 0)
    pre_w = *(const f32x4*)&wtv[colb];
  if constexpr (MODE == 1 || MODE == 2 || MODE == 3)
    pre_z = *(const f32x4*)&Zbuf[oidx];
  if constexpr (MODE == 2 || MODE == 3 || MODE == 4)
    pre_a = *(const f32x4*)&Zacc[oidx];
  // pin the load issue before the K-loop (compiler may not sink them)
  asm volatile("" :: "v"(pre_b[0]), "v"(pre_w[0]), "v"(pre_z[0]), "v"(pre_a[0]));

  f32x4 a00={0.f,0.f,0.f,0.f}, a01=a00, a10=a00, a11=a00;

  STAGE(0, 0);
  __syncthreads();
  #pragma unroll
  for (int kt = 0; kt < 8; ++kt){
    const int cur = kt & 1;
    if (kt < 7) STAGE(cur ^ 1, kt + 1);
    const char* L = Lraw + cur*32768;
    short8 ah0 = *(const short8*)(L + ro);
    short8 ah1 = *(const short8*)(L + 4096  + ro);
    short8 al0 = *(const short8*)(L + 8192  + ro);
    short8 al1 = *(const short8*)(L + 12288 + ro);
    short8 bh0 = *(const short8*)(L + 16384 + ro);
    short8 bh1 = *(const short8*)(L + 20480 + ro);
    short8 bl0 = *(const short8*)(L + 24576 + ro);
    short8 bl1 = *(const short8*)(L + 28672 + ro);
    __builtin_amdgcn_s_setprio(1);
    a00 = __builtin_amdgcn_mfma_f32_16x16x32_bf16(ah0, bh0, a00, 0,0,0);
    a01 = __builtin_amdgcn_mfma_f32_16x16x32_bf16(ah0, bh1, a01, 0,0,0);
    a10 = __builtin_amdgcn_mfma_f32_16x16x32_bf16(ah1, bh0, a10, 0,0,0);
    a11 = __builtin_amdgcn_mfma_f32_16x16x32_bf16(ah1, bh1, a11, 0,0,0);
    a00 = __builtin_amdgcn_mfma_f32_16x16x32_bf16(al0, bh0, a00, 0,0,0);
    a01 = __builtin_amdgcn_mfma_f32_16x16x32_bf16(al0, bh1, a01, 0,0,0);
    a10 = __builtin_amdgcn_mfma_f32_16x16x32_bf16(al1, bh0, a10, 0,0,0);
    a11 = __builtin_amdgcn_mfma_f32_16x16x32_bf16(al1, bh1, a11, 0,0,0);
    a00 = __builtin_amdgcn_mfma_f32_16x16x32_bf16(ah0, bl0, a00, 0,0,0);
    a01 = __builtin_amdgcn_mfma_f32_16x16x32_bf16(ah0, bl1, a01, 0,0,0);
    a10 = __builtin_amdgcn_mfma_f32_16x16x32_bf16(ah1, bl0, a10, 0,0,0);
    a11 = __builtin_amdgcn_mfma_f32_16x16x32_bf16(ah1, bl1, a11, 0,0,0);
    __builtin_amdgcn_s_setprio(0);
    __syncthreads();
  }

  // ---- deposit kq-partials into aliased red[4][32][36] (final tile was buf1) ----
  // C/D: col=lane&15, row=(lane>>4)*4+i  [m89]
  #pragma unroll
  for (int i=0;i<4;++i){
    red[(kq*32 + ks*4 + i)*36 + lr]           = a00[i];
    red[(kq*32 + ks*4 + i)*36 + 16 + lr]      = a01[i];
    red[(kq*32 + 16 + ks*4 + i)*36 + lr]      = a10[i];
    red[(kq*32 + 16 + ks*4 + i)*36 + 16 + lr] = a11[i];
  }
  __syncthreads();

  // ---- reduce + fused epilogue: thread -> (row rr, cols c4..c4+3) ----
  f32x4 s = *(const f32x4*)&red[(0*32 + rr)*36 + c4];
  s += *(const f32x4*)&red[(1*32 + rr)*36 + c4];
  s += *(const f32x4*)&red[(2*32 + rr)*36 + c4];
  s += *(const f32x4*)&red[(3*32 + rr)*36 + c4];

  const float t0 = tvec[step], t1v = tvec[step+1];
  const float dt = t1v - t0, half = 0.5f*dt;

  short4_t oh, ol;
  if constexpr (MODE == 0){
    const float ti = (which == 0) ? t0 : ((which == 3) ? t1v : (t0 + half));
    #pragma unroll
    for (int j=0;j<4;++j){
      float hv = tanhf(s[j] + pre_b[j] + ti*pre_w[j]);
      u16 h,l; splitw(hv,h,l);
      oh[j] = (short)h; ol[j] = (short)l;
    }
  } else {
    constexpr int S = MODE - 1;
    const float dt6 = dt*(1.0f/6.0f), dt3 = dt*(1.0f/3.0f);
    const f32x4 kv = s + pre_b;
    f32x4 zm;
    if constexpr (S == 0){
      zm = pre_z + half*kv;
      *(f32x4*)&Zacc[oidx] = pre_z + dt6*kv;
    } else if constexpr (S == 1){
      zm = pre_z + half*kv;
      *(f32x4*)&Zacc[oidx] = pre_a + dt3*kv;
    } else if constexpr (S == 2){
      zm = pre_z + dt*kv;
      *(f32x4*)&Zacc[oidx] = pre_a + dt3*kv;
    } else {
      zm = pre_a + dt6*kv;
      *(f32x4*)&Zbuf[oidx] = zm;               // z (== d_out)
    }
    #pragma unroll
    for (int j=0;j<4;++j){
      u16 h,l; splitw(zm[j],h,l);
      oh[j] = (short)h; ol[j] = (short)l;
    }
  }
  *(short4_t*)&OutHi[oidx] = oh;
  *(short4_t*)&OutLo[oidx] = ol;
}

extern "C" void kernel_launch(void* const* d_in, const int* in_sizes, int n_in,
                              void* d_out, int out_size, void* d_ws, size_t ws_size,
                              hipStream_t stream)
{
  (void)in_sizes; (void)n_in; (void)out_size; (void)ws_size;
  const float* z_init = (const float*)d_in[0];
  const float* tvec   = (const float*)d_in[1];
  const float* W1     = (const float*)d_in[2];
  const float* b1     = (const float*)d_in[3];
  const float* wt     = (const float*)d_in[4];
  const float* W2     = (const float*)d_in[5];
  const float* b2     = (const float*)d_in[6];
  float* z = (float*)d_out;                    // fp32 master state lives in d_out

  char* p = (char*)d_ws;
  const size_t EL = 512*1024;
  u16* zh  = (u16*)p; p += EL*2;
  u16* zl  = (u16*)p; p += EL*2;
  u16* zmh = (u16*)p; p += EL*2;
  u16* zml = (u16*)p; p += EL*2;
  u16* hh  = (u16*)p; p += EL*2;
  u16* hl  = (u16*)p; p += EL*2;
  float* zacc = (float*)p; p += EL*4;
  u16* W1h = (u16*)p; p += (size_t)1024*1024*2;
  u16* W1l = (u16*)p; p += (size_t)1024*1024*2;
  u16* W2h = (u16*)p; p += (size_t)1024*1024*2;
  u16* W2l = (u16*)p; p += (size_t)1024*1024*2;

  prep_weights<<<dim3(32,32),256,0,stream>>>(W1, W1h, W1l);
  prep_weights<<<dim3(32,32),256,0,stream>>>(W2, W2h, W2l);
  init_z<<<2048,256,0,stream>>>(z_init, z, zh, zl);

  for (int step=0; step<32; ++step){
    for (int s=0; s<4; ++s){
      const u16* ah = (s==0)? zh : zmh;
      const u16* al = (s==0)? zl : zml;
      fused_gemm<0><<<NGRID,BDIM,0,stream>>>(ah, al, W1h, W1l, b1, wt, tvec, step, s,
                                             hh, hl, nullptr, nullptr);
      u16* oh = (s==3)? zh : zmh;
      u16* ol = (s==3)? zl : zml;
      switch (s){
        case 0: fused_gemm<1><<<NGRID,BDIM,0,stream>>>(hh, hl, W2h, W2l, b2, nullptr, tvec, step, s, oh, ol, z, zacc); break;
        case 1: fused_gemm<2><<<NGRID,BDIM,0,stream>>>(hh, hl, W2h, W2l, b2, nullptr, tvec, step, s, oh, ol, z, zacc); break;
        case 2: fused_gemm<3><<<NGRID,BDIM,0,stream>>>(hh, hl, W2h, W2l, b2, nullptr, tvec, step, s, oh, ol, z, zacc); break;
        case 3: fused_gemm<4><<<NGRID,BDIM,0,stream>>>(hh, hl, W2h, W2l, b2, nullptr, tvec, step, s, oh, ol, z, zacc); break;
      }
    }
  }
}